// Round 9
// baseline (541.454 us; speedup 1.0000x reference)
//
#include <hip/hip_runtime.h>

typedef short short8 __attribute__((ext_vector_type(8)));
typedef float f32x4 __attribute__((ext_vector_type(4)));

#define SEQ 2048
#define QSCALE 0.18033688011112042f   // 0.125 * log2(e): softmax done in base 2
#define PSHIFT 20.0f                  // fixed softmax shift (cancels in O = acc/l)
#define EXP2(x) __builtin_amdgcn_exp2f(x)

__device__ __forceinline__ unsigned short f2bf(float f) {
    unsigned int u = __builtin_bit_cast(unsigned int, f);
    unsigned int r = (u + 0x7fffu + ((u >> 16) & 1u)) >> 16;
    return (unsigned short)r;
}

// ---------------------------------------------------------------------------
// Batched weight transpose + fp32->bf16: 8 D x D weights in one launch.
// ---------------------------------------------------------------------------
__global__ __launch_bounds__(256)
void wtrans8_kernel(const float* w0, const float* w1, const float* w2, const float* w3,
                    const float* w4, const float* w5, const float* w6, const float* w7,
                    unsigned short* __restrict__ outbase)
{
    const float* Ws[8] = {w0, w1, w2, w3, w4, w5, w6, w7};
    const float* __restrict__ W = Ws[blockIdx.z];
    unsigned short* __restrict__ Wt = outbase + (size_t)blockIdx.z * 1024 * 1024;
    __shared__ float t[32][33];
    const int tx = threadIdx.x & 31;
    const int ty = threadIdx.x >> 5;
    const int nb = blockIdx.x * 32;
    const int kb = blockIdx.y * 32;
#pragma unroll
    for (int i = 0; i < 4; i++)
        t[ty + i * 8][tx] = W[(size_t)(kb + ty + i * 8) * 1024 + nb + tx];
    __syncthreads();
#pragma unroll
    for (int i = 0; i < 4; i++)
        Wt[(size_t)(nb + ty + i * 8) * 1024 + kb + tx] = f2bf(t[tx][ty + i * 8]);
}

// single weight transpose (for the two FFN shapes)
__global__ __launch_bounds__(256)
void wtrans_kernel(const float* __restrict__ W, unsigned short* __restrict__ Wt,
                   int Kd, int Nd)
{
    __shared__ float t[32][33];
    const int tx = threadIdx.x & 31;
    const int ty = threadIdx.x >> 5;
    const int nb = blockIdx.x * 32;
    const int kb = blockIdx.y * 32;
#pragma unroll
    for (int i = 0; i < 4; i++)
        t[ty + i * 8][tx] = W[(size_t)(kb + ty + i * 8) * Nd + nb + tx];
    __syncthreads();
#pragma unroll
    for (int i = 0; i < 4; i++)
        Wt[(size_t)(nb + ty + i * 8) * Kd + kb + tx] = f2bf(t[tx][ty + i * 8]);
}

// ---------------------------------------------------------------------------
// Elementwise fp32 -> bf16
// ---------------------------------------------------------------------------
__global__ __launch_bounds__(256)
void cvt_kernel(const float* __restrict__ in, unsigned short* __restrict__ out, int n)
{
    int i = (blockIdx.x * 256 + threadIdx.x) * 4;
    if (i < n) {
        float4 v = *(const float4*)(in + i);
        ushort4 o;
        o.x = f2bf(v.x); o.y = f2bf(v.y); o.z = f2bf(v.z); o.w = f2bf(v.w);
        *(ushort4*)(out + i) = o;
    }
}

// ---------------------------------------------------------------------------
// LayerNorm (torch-faithful: ddof=1, eps added to std). fp32 in -> bf16 out.
// ---------------------------------------------------------------------------
__global__ __launch_bounds__(256)
void ln_kernel(const float* __restrict__ x, const float* __restrict__ g,
               const float* __restrict__ bb, unsigned short* __restrict__ out)
{
    const int D = 1024;
    const int row = blockIdx.x;
    const float* xr = x + (size_t)row * D;
    float v[4];
    float s = 0.f, ss = 0.f;
#pragma unroll
    for (int i = 0; i < 4; i++) {
        v[i] = xr[threadIdx.x + i * 256];
        s += v[i];
        ss += v[i] * v[i];
    }
#pragma unroll
    for (int off = 1; off < 64; off <<= 1) {
        s  += __shfl_xor(s,  off, 64);
        ss += __shfl_xor(ss, off, 64);
    }
    __shared__ float red[8];
    const int wave = threadIdx.x >> 6;
    if ((threadIdx.x & 63) == 0) { red[wave] = s; red[4 + wave] = ss; }
    __syncthreads();
    s  = red[0] + red[1] + red[2] + red[3];
    ss = red[4] + red[5] + red[6] + red[7];
    float mean = s / D;
    float var  = fmaxf((ss - s * mean) / (D - 1), 0.f);
    float inv  = 1.f / (sqrtf(var) + 1e-6f);
#pragma unroll
    for (int i = 0; i < 4; i++) {
        int c = threadIdx.x + i * 256;
        out[(size_t)row * D + c] = f2bf(g[c] * (v[i] - mean) * inv + bb[c]);
    }
}

// ---------------------------------------------------------------------------
// Register-staged double-buffered GEMM (round-4-proven transport) for the
// QKV projection and FFN1 shapes. C[M,N] = A[M,K] @ Wt[N,K]^T + bias.
// 128x128 tile, BK=64, 4 waves, 2 LDS buffers. Per K-step: issue next
// tile's global_load_dwordx4 -> VGPR before compute (latency hides under
// 32 MFMA), vmcnt(0) + linear ds_write_b128 after, one barrier.
// MODE 1: projection GEMM. Section = n0>>10: 0 -> Q (from A, scaled QSCALE,
//         head layout [B,H,S,64]); 1 -> K (from A2); 2 -> V (from A2,
//         written TRANSPOSED [B,H,64,S]).
// MODE 2: relu -> bf16 row-major [M,N]    (FFN first GEMM, o0)
// ---------------------------------------------------------------------------
template <int MODE>
__global__ __launch_bounds__(256, 1)
void gemm_rs_kernel(const unsigned short* __restrict__ A,
                    const unsigned short* __restrict__ A2,
                    const unsigned short* __restrict__ Wt,
                    const float* __restrict__ b0,
                    const float* __restrict__ b1,
                    const float* __restrict__ b2,
                    unsigned short* __restrict__ o0,
                    unsigned short* __restrict__ o1,
                    unsigned short* __restrict__ o2,
                    int M, int N, int K)
{
    __shared__ unsigned short As[2][128 * 64];
    __shared__ unsigned short Bs[2][128 * 64];
    const int tid  = threadIdx.x;
    const int lane = tid & 63;
    const int wv   = tid >> 6;
    const int quad = lane >> 4;
    const int l16  = lane & 15;
    const int m0 = blockIdx.y * 128;
    const int n0 = blockIdx.x * 128;
    const int wm = (wv >> 1) << 6;
    const int wn = (wv & 1) << 6;
    const int sect = (MODE == 1) ? (n0 >> 10) : 0;
    const unsigned short* Asel = (MODE == 1 && sect != 0) ? A2 : A;

    const int rsub = lane >> 3;                    // 0..7 row within chunk
    const int cu8  = ((lane & 7) ^ rsub) * 8;      // swizzled source col (elems)
    const unsigned short* Ag = Asel + (size_t)(m0 + wv * 32 + rsub) * K + cu8;
    const unsigned short* Bg = Wt   + (size_t)(n0 + wv * 32 + rsub) * K + cu8;

    f32x4 acc[4][4];
#pragma unroll
    for (int i = 0; i < 4; i++)
#pragma unroll
        for (int j = 0; j < 4; j++) acc[i][j] = f32x4{0.f, 0.f, 0.f, 0.f};

    const int NT = K >> 6;

    short8 ar[4], br[4];   // in-flight staging registers (one tile)

    auto ldregs = [&](int t) {
        const int kb = t << 6;
#pragma unroll
        for (int r = 0; r < 4; r++) {
            ar[r] = *(const short8*)(Ag + (size_t)(r * 8) * K + kb);
            br[r] = *(const short8*)(Bg + (size_t)(r * 8) * K + kb);
        }
    };
    auto wrlds = [&](int b) {
#pragma unroll
        for (int r = 0; r < 4; r++) {
            *(short8*)&As[b][(wv * 4 + r) * 512 + lane * 8] = ar[r];
            *(short8*)&Bs[b][(wv * 4 + r) * 512 + lane * 8] = br[r];
        }
    };

    // prologue: tile 0 -> regs -> LDS[0]
    ldregs(0);
    asm volatile("s_waitcnt vmcnt(0)" ::: "memory");
    wrlds(0);
    asm volatile("s_waitcnt lgkmcnt(0)" ::: "memory");
    __builtin_amdgcn_s_barrier();

    for (int i = 0; i < NT; i++) {
        const int cur = i & 1;
        if (i + 1 < NT) ldregs(i + 1);   // issue early: latency under compute

#pragma unroll
        for (int ks = 0; ks < 2; ks++) {
            short8 af[4], bfr[4];
#pragma unroll
            for (int mi = 0; mi < 4; mi++)
                af[mi] = *(const short8*)(&As[cur][(wm + mi * 16 + l16) * 64 +
                             (((ks * 4 + quad) ^ (l16 & 7)) * 8)]);
#pragma unroll
            for (int ni = 0; ni < 4; ni++)
                bfr[ni] = *(const short8*)(&Bs[cur][(wn + ni * 16 + l16) * 64 +
                             (((ks * 4 + quad) ^ (l16 & 7)) * 8)]);
#pragma unroll
            for (int mi = 0; mi < 4; mi++)
#pragma unroll
                for (int ni = 0; ni < 4; ni++)
                    acc[mi][ni] = __builtin_amdgcn_mfma_f32_16x16x32_bf16(
                        af[mi], bfr[ni], acc[mi][ni], 0, 0, 0);
        }

        if (i + 1 < NT) {
            asm volatile("s_waitcnt vmcnt(0)" ::: "memory");
            wrlds(cur ^ 1);
            asm volatile("s_waitcnt lgkmcnt(0)" ::: "memory");
            __builtin_amdgcn_s_barrier();
        }
    }

    if (MODE == 1) {
        const float* bias = (sect == 0) ? b0 : ((sect == 1) ? b1 : b2);
        if (sect == 2) {
            // V: write transposed [B,H,64,S], 4 consecutive s packed per store
#pragma unroll
            for (int mi = 0; mi < 4; mi++)
#pragma unroll
                for (int ni = 0; ni < 4; ni++) {
                    const int cc = (n0 + wn + ni * 16 + l16) & 1023;
                    const int h = cc >> 6, d = cc & 63;
                    const float bv = bias[cc];
                    const int rowg = m0 + wm + mi * 16 + quad * 4;
                    const int b = rowg >> 11, s = rowg & 2047;
                    ushort4 o4;
                    o4.x = f2bf(acc[mi][ni][0] + bv);
                    o4.y = f2bf(acc[mi][ni][1] + bv);
                    o4.z = f2bf(acc[mi][ni][2] + bv);
                    o4.w = f2bf(acc[mi][ni][3] + bv);
                    *(ushort4*)&o2[((size_t)(b * 16 + h) * 64 + d) * SEQ + s] = o4;
                }
        } else {
            unsigned short* dst = (sect == 0) ? o0 : o1;
            const float scl = (sect == 0) ? QSCALE : 1.0f;
#pragma unroll
            for (int mi = 0; mi < 4; mi++)
#pragma unroll
                for (int ni = 0; ni < 4; ni++) {
                    const int cc = (n0 + wn + ni * 16 + l16) & 1023;
                    const int h = cc >> 6, d = cc & 63;
                    const float bv = bias[cc];
#pragma unroll
                    for (int r = 0; r < 4; r++) {
                        const int rowg = m0 + wm + mi * 16 + quad * 4 + r;
                        const int b = rowg >> 11, s = rowg & 2047;
                        float v = (acc[mi][ni][r] + bv) * scl;
                        dst[((size_t)(b * 16 + h) * SEQ + s) * 64 + d] = f2bf(v);
                    }
                }
        }
    } else {
#pragma unroll
        for (int mi = 0; mi < 4; mi++)
#pragma unroll
            for (int ni = 0; ni < 4; ni++) {
                const int colg = n0 + wn + ni * 16 + l16;
                const float bv = b0[colg];
#pragma unroll
                for (int r = 0; r < 4; r++) {
                    const int rowg = m0 + wm + mi * 16 + quad * 4 + r;
                    float v = acc[mi][ni][r] + bv;
                    o0[(size_t)rowg * N + colg] = f2bf(fmaxf(v, 0.f));
                }
            }
    }
}

// ---------------------------------------------------------------------------
// Register-staged double-buffered GEMM for the N=1024 shapes (round-4 WIN:
// reg-staging >> global_load_lds at 1-2 blocks/CU).
// C[M,N] = A[M,K] @ Wt[N,K]^T + bias + res   (fp32 out, fused residual)
// 128x128 tile, BK=64, 4 waves, 2 LDS buffers.
// XCD rectangle partition (cm x cn tiles per XCD): FETCH 143 -> 57 MB.
// LDS reads XOR-swizzled; swizzle pre-applied to global source addr.
// ---------------------------------------------------------------------------
__global__ __launch_bounds__(256, 1)
void gemm_db_kernel(const unsigned short* __restrict__ A,
                    const unsigned short* __restrict__ Wt,
                    const float* __restrict__ b0,
                    const float* __restrict__ res,
                    float* __restrict__ outf,
                    int M, int N, int K, int cm, int cn)
{
    __shared__ unsigned short As[2][128 * 64];
    __shared__ unsigned short Bs[2][128 * 64];
    const int tid  = threadIdx.x;
    const int lane = tid & 63;
    const int wv   = tid >> 6;
    const int quad = lane >> 4;
    const int l16  = lane & 15;
    // XCD partition: id%8 == XCD (round-robin dispatch heuristic)
    const int NX  = gridDim.x;
    const int id  = blockIdx.y * NX + blockIdx.x;
    const int xcd = id & 7, slot = id >> 3;
    const int ngx = NX / cn;                 // #col-groups of XCD rectangles
    const int rg = xcd / ngx, cg = xcd - rg * ngx;
    const int m0 = (rg * cm + (slot % cm)) * 128;
    const int n0 = (cg * cn + (slot / cm)) * 128;
    const int wm = (wv >> 1) << 6;
    const int wn = (wv & 1) << 6;

    const int rsub = lane >> 3;                    // 0..7 row within chunk
    const int cu8  = ((lane & 7) ^ rsub) * 8;      // swizzled source col (elems)
    const unsigned short* Ag = A  + (size_t)(m0 + wv * 32 + rsub) * K + cu8;
    const unsigned short* Bg = Wt + (size_t)(n0 + wv * 32 + rsub) * K + cu8;

    f32x4 acc[4][4];
#pragma unroll
    for (int i = 0; i < 4; i++)
#pragma unroll
        for (int j = 0; j < 4; j++) acc[i][j] = f32x4{0.f, 0.f, 0.f, 0.f};

    const int NT = K >> 6;

    short8 ar[4], br[4];   // in-flight staging registers (one tile)

    auto ldregs = [&](int t) {
        const int kb = t << 6;
#pragma unroll
        for (int r = 0; r < 4; r++) {
            ar[r] = *(const short8*)(Ag + (size_t)(r * 8) * K + kb);
            br[r] = *(const short8*)(Bg + (size_t)(r * 8) * K + kb);
        }
    };
    auto wrlds = [&](int b) {
#pragma unroll
        for (int r = 0; r < 4; r++) {
            *(short8*)&As[b][(wv * 4 + r) * 512 + lane * 8] = ar[r];
            *(short8*)&Bs[b][(wv * 4 + r) * 512 + lane * 8] = br[r];
        }
    };

    // prologue: tile 0 -> regs -> LDS[0]
    ldregs(0);
    asm volatile("s_waitcnt vmcnt(0)" ::: "memory");
    wrlds(0);
    asm volatile("s_waitcnt lgkmcnt(0)" ::: "memory");
    __builtin_amdgcn_s_barrier();

    for (int i = 0; i < NT; i++) {
        const int cur = i & 1;
        if (i + 1 < NT) ldregs(i + 1);   // issue early: latency under compute

        // compute buffer cur: 2 K-slices x 16 MFMA
#pragma unroll
        for (int ks = 0; ks < 2; ks++) {
            short8 af[4], bfr[4];
#pragma unroll
            for (int mi = 0; mi < 4; mi++)
                af[mi] = *(const short8*)(&As[cur][(wm + mi * 16 + l16) * 64 +
                             (((ks * 4 + quad) ^ (l16 & 7)) * 8)]);
#pragma unroll
            for (int ni = 0; ni < 4; ni++)
                bfr[ni] = *(const short8*)(&Bs[cur][(wn + ni * 16 + l16) * 64 +
                             (((ks * 4 + quad) ^ (l16 & 7)) * 8)]);
#pragma unroll
            for (int mi = 0; mi < 4; mi++)
#pragma unroll
                for (int ni = 0; ni < 4; ni++)
                    acc[mi][ni] = __builtin_amdgcn_mfma_f32_16x16x32_bf16(
                        af[mi], bfr[ni], acc[mi][ni], 0, 0, 0);
        }

        if (i + 1 < NT) {
            // regs arrived during compute; publish to the other buffer
            asm volatile("s_waitcnt vmcnt(0)" ::: "memory");
            wrlds(cur ^ 1);
            asm volatile("s_waitcnt lgkmcnt(0)" ::: "memory");
            __builtin_amdgcn_s_barrier();   // buffer cur^1 ready for all
        }
    }

    // epilogue: bias + fused residual, fp32 out
#pragma unroll
    for (int mi = 0; mi < 4; mi++)
#pragma unroll
        for (int ni = 0; ni < 4; ni++) {
            const int colg = n0 + wn + ni * 16 + l16;
            const float bv = b0[colg];
#pragma unroll
            for (int r = 0; r < 4; r++) {
                const int rowg = m0 + wm + mi * 16 + quad * 4 + r;
                outf[(size_t)rowg * N + colg] =
                    acc[mi][ni][r] + bv + res[(size_t)rowg * N + colg];
            }
        }
}

// ---------------------------------------------------------------------------
// Flash attention v4d: round-7 code (known-good values, f2bf P-store kept
// byte-identical) with ONE change: Ks fragment loads hoisted out of the qs
// loop (they are qs-invariant) -> 32 -> 16 ds_read_b128 per tile. Pure
// reordering: same addresses, same values; costs scf[2][8] live (VGPR +32).
// NOTE: v_cvt_pk_bf16_f32 hand-asm is BANNED here -- it produced garbage in
// rounds 5/6/8 (per m240: compiler handles bf16 cvt; don't hand-write it).
// ---------------------------------------------------------------------------
template <bool CAUSAL>
__global__ __launch_bounds__(256, 2)
void attn4_kernel(const unsigned short* __restrict__ Q,
                  const unsigned short* __restrict__ K,
                  const unsigned short* __restrict__ VT,
                  unsigned short* __restrict__ O)
{
    __shared__ unsigned short Ks[128 * 72];
    __shared__ unsigned short Vt[64 * 136];
    __shared__ unsigned short Ps[4][32 * 136];
    __shared__ float sumS[4][32];
    const int tid  = threadIdx.x;
    const int lane = tid & 63;
    const int wave = tid >> 6;
    const int quad = lane >> 4;
    const int l16  = lane & 15;
    const int bh = blockIdx.y;
    // causal: pair heavy with light so each CU's two blocks sum to 17 tiles
    const int qb = (CAUSAL && (bh & 16)) ? (15 - (int)blockIdx.x) : (int)blockIdx.x;
    const int q0 = qb * 128;
    const size_t baseK = (size_t)bh * SEQ * 64;
    const size_t baseV = (size_t)bh * 64 * SEQ;

    short8 aq[2][2];
#pragma unroll
    for (int qs = 0; qs < 2; qs++) {
        const unsigned short* qp =
            Q + baseK + (size_t)(q0 + wave * 32 + qs * 16 + l16) * 64 + quad * 8;
        aq[qs][0] = *(const short8*)(qp);
        aq[qs][1] = *(const short8*)(qp + 32);
    }
    f32x4 acc[4][2];   // [mi(d)][qs]: O^T row d=mi*16+quad*4+r, col q=l16
#pragma unroll
    for (int i = 0; i < 4; i++)
#pragma unroll
        for (int j = 0; j < 2; j++) acc[i][j] = f32x4{0.f, 0.f, 0.f, 0.f};
    float lsum[2][4] = {{0.f, 0.f, 0.f, 0.f}, {0.f, 0.f, 0.f, 0.f}};

    const int nkb = CAUSAL ? (qb + 1) : (SEQ / 128);
    const int krow = tid >> 1;
    const int kc   = (tid & 1) * 32;
    const int vrow = tid >> 2;
    const int vc   = (tid & 3) * 32;
    const unsigned short* kg = K  + baseK + (size_t)krow * 64 + kc;
    const unsigned short* vg = VT + baseV + (size_t)vrow * SEQ + vc;

    short8 kr0 = *(const short8*)(kg),      kr1 = *(const short8*)(kg + 8);
    short8 kr2 = *(const short8*)(kg + 16), kr3 = *(const short8*)(kg + 24);
    short8 vr0 = *(const short8*)(vg),      vr1 = *(const short8*)(vg + 8);
    short8 vr2 = *(const short8*)(vg + 16), vr3 = *(const short8*)(vg + 24);

    for (int kb = 0; kb < nkb; kb++) {
        __syncthreads();
        *(short8*)&Ks[krow * 72 + kc]      = kr0;
        *(short8*)&Ks[krow * 72 + kc + 8]  = kr1;
        *(short8*)&Ks[krow * 72 + kc + 16] = kr2;
        *(short8*)&Ks[krow * 72 + kc + 24] = kr3;
        *(short8*)&Vt[vrow * 136 + vc]      = vr0;
        *(short8*)&Vt[vrow * 136 + vc + 8]  = vr1;
        *(short8*)&Vt[vrow * 136 + vc + 16] = vr2;
        *(short8*)&Vt[vrow * 136 + vc + 24] = vr3;
        if (kb + 1 < nkb) {
            const unsigned short* kg2 = kg + (size_t)(kb + 1) * 128 * 64;
            const unsigned short* vg2 = vg + (size_t)(kb + 1) * 128;
            kr0 = *(const short8*)(kg2);      kr1 = *(const short8*)(kg2 + 8);
            kr2 = *(const short8*)(kg2 + 16); kr3 = *(const short8*)(kg2 + 24);
            vr0 = *(const short8*)(vg2);      vr1 = *(const short8*)(vg2 + 8);
            vr2 = *(const short8*)(vg2 + 16); vr3 = *(const short8*)(vg2 + 24);
        }
        __syncthreads();

        const bool maskTile = CAUSAL && (kb == nkb - 1);
        // QK^T: Ks fragments are qs-invariant -> load once, use for both qs
        f32x4 scf[2][8];
#pragma unroll
        for (int nt = 0; nt < 8; nt++) {
            short8 bk0 = *(const short8*)(&Ks[(nt * 16 + l16) * 72 + quad * 8]);
            short8 bk1 = *(const short8*)(&Ks[(nt * 16 + l16) * 72 + 32 + quad * 8]);
#pragma unroll
            for (int qs = 0; qs < 2; qs++) {
                f32x4 z = f32x4{0.f, 0.f, 0.f, 0.f};
                z = __builtin_amdgcn_mfma_f32_16x16x32_bf16(aq[qs][0], bk0, z, 0, 0, 0);
                z = __builtin_amdgcn_mfma_f32_16x16x32_bf16(aq[qs][1], bk1, z, 0, 0, 0);
                scf[qs][nt] = z;
            }
        }
#pragma unroll
        for (int qs = 0; qs < 2; qs++) {
            if (maskTile) {
                const int qg = q0 + wave * 32 + qs * 16 + quad * 4;
                const int k0 = kb * 128;
#pragma unroll
                for (int nt = 0; nt < 8; nt++) {
                    const int kg_ = k0 + nt * 16 + l16;
#pragma unroll
                    for (int r = 0; r < 4; r++)
                        if (kg_ > qg + r) scf[qs][nt][r] = -1e9f;
                }
            }
#pragma unroll
            for (int nt = 0; nt < 8; nt++)
#pragma unroll
                for (int r = 0; r < 4; r++) {
                    float pv = EXP2(scf[qs][nt][r] - PSHIFT);
                    lsum[qs][r] += pv;
                    Ps[wave][(qs * 16 + quad * 4 + r) * 136 +
                             ((nt * 16 + l16) ^ (quad * 8))] = f2bf(pv);
                }
        }
        // O^T += V^T @ P^T, both operands contiguous b128; Vt reads shared
        const int pswz = 8 * (quad ^ ((l16 >> 2) & 3));
#pragma unroll
        for (int c = 0; c < 4; c++) {
            short8 av[4];
#pragma unroll
            for (int mi = 0; mi < 4; mi++)
                av[mi] = *(const short8*)(&Vt[(mi * 16 + l16) * 136 + c * 32 + quad * 8]);
#pragma unroll
            for (int qs = 0; qs < 2; qs++) {
                short8 bp = *(const short8*)(&Ps[wave][(qs * 16 + l16) * 136 + c * 32 + pswz]);
#pragma unroll
                for (int mi = 0; mi < 4; mi++)
                    acc[mi][qs] = __builtin_amdgcn_mfma_f32_16x16x32_bf16(av[mi], bp, acc[mi][qs], 0, 0, 0);
            }
        }
    }
#pragma unroll
    for (int qs = 0; qs < 2; qs++)
#pragma unroll
        for (int r = 0; r < 4; r++) {
#pragma unroll
            for (int off = 1; off < 16; off <<= 1)
                lsum[qs][r] += __shfl_xor(lsum[qs][r], off, 64);
        }
    if (l16 == 0) {
#pragma unroll
        for (int qs = 0; qs < 2; qs++)
#pragma unroll
            for (int r = 0; r < 4; r++)
                sumS[wave][qs * 16 + quad * 4 + r] = lsum[qs][r];
    }
    __syncthreads();
    const int b = bh >> 4, h = bh & 15;
#pragma unroll
    for (int qs = 0; qs < 2; qs++) {
        const float rcpL = 1.f / sumS[wave][qs * 16 + l16];
        const int qg = q0 + wave * 32 + qs * 16 + l16;
#pragma unroll
        for (int mi = 0; mi < 4; mi++) {
            ushort4 o4;
            o4.x = f2bf(acc[mi][qs][0] * rcpL);
            o4.y = f2bf(acc[mi][qs][1] * rcpL);
            o4.z = f2bf(acc[mi][qs][2] * rcpL);
            o4.w = f2bf(acc[mi][qs][3] * rcpL);
            *(ushort4*)&O[(size_t)(b * SEQ + qg) * 1024 + h * 64 + mi * 16 + quad * 4] = o4;
        }
    }
}

// ---------------------------------------------------------------------------
extern "C" void kernel_launch(void* const* d_in, const int* in_sizes, int n_in,
                              void* d_out, int out_size, void* d_ws, size_t ws_size,
                              hipStream_t stream)
{
    (void)in_sizes; (void)n_in; (void)out_size; (void)ws_size;
    const int B = 2, S = SEQ, D = 1024, DFF = 4096;
    const int M = B * S;  // 4096

    const float* x     = (const float*)d_in[0];
    const float* enc   = (const float*)d_in[1];
    const float* sa_wq = (const float*)d_in[4],  *sa_bq = (const float*)d_in[5];
    const float* sa_wk = (const float*)d_in[6],  *sa_bk = (const float*)d_in[7];
    const float* sa_wv = (const float*)d_in[8],  *sa_bv = (const float*)d_in[9];
    const float* sa_wo = (const float*)d_in[10], *sa_bo = (const float*)d_in[11];
    const float* ca_wq = (const float*)d_in[12], *ca_bq = (const float*)d_in[13];
    const float* ca_wk = (const float*)d_in[14], *ca_bk = (const float*)d_in[15];
    const float* ca_wv = (const float*)d_in[16], *ca_bv = (const float*)d_in[17];
    const float* ca_wo = (const float*)d_in[18], *ca_bo = (const float*)d_in[19];
    const float* ff_w1 = (const float*)d_in[20], *ff_b1 = (const float*)d_in[21];
    const float* ff_w2 = (const float*)d_in[22], *ff_b2 = (const float*)d_in[23];
    const float* n1_g  = (const float*)d_in[24], *n1_b = (const float*)d_in[25];
    const float* n2_g  = (const float*)d_in[26], *n2_b = (const float*)d_in[27];
    const float* n3_g  = (const float*)d_in[28], *n3_b = (const float*)d_in[29];
    float* out = (float*)d_out;

    char* p = (char*)d_ws;
    auto carve = [&](size_t bytes) -> char* {
        char* r = p;
        p += (bytes + 255) & ~(size_t)255;
        return r;
    };
    unsigned short* wt8     = (unsigned short*)carve((size_t)8 * D * D * 2);
    unsigned short* wt_sqkv = wt8;                       // saq, sak, sav contiguous
    unsigned short* wt_sao  = wt8 + (size_t)3 * D * D;
    unsigned short* wt_cqkv = wt8 + (size_t)4 * D * D;   // caq, cak, cav contiguous
    unsigned short* wt_cao  = wt8 + (size_t)7 * D * D;
    unsigned short* wt_ff1  = (unsigned short*)carve((size_t)D * DFF * 2);
    unsigned short* wt_ff2  = (unsigned short*)carve((size_t)DFF * D * 2);
    unsigned short* encb    = (unsigned short*)carve((size_t)M * D * 2);
    unsigned short* hb      = (unsigned short*)carve((size_t)M * D * 2);
    unsigned short* qbuf    = (unsigned short*)carve((size_t)M * D * 2);
    unsigned short* kbuf    = (unsigned short*)carve((size_t)M * D * 2);
    unsigned short* vtbuf   = (unsigned short*)carve((size_t)M * D * 2);
    unsigned short* ffh     = (unsigned short*)carve((size_t)M * DFF * 2);
    float* x1 = (float*)carve((size_t)M * D * 4);
    unsigned short* abuf = hb;   // lifetimes disjoint
    float* x2 = out;             // block-2 residual in d_out; block-3 in-place

    dim3 blk(256);
    wtrans8_kernel<<<dim3(32, 32, 8), blk, 0, stream>>>(
        sa_wq, sa_wk, sa_wv, sa_wo, ca_wq, ca_wk, ca_wv, ca_wo, wt8);
    wtrans_kernel<<<dim3(DFF / 32, D / 32), blk, 0, stream>>>(ff_w1, wt_ff1, D, DFF);
    wtrans_kernel<<<dim3(D / 32, DFF / 32), blk, 0, stream>>>(ff_w2, wt_ff2, DFF, D);
    cvt_kernel<<<dim3(M * D / 1024), blk, 0, stream>>>(enc, encb, M * D);

    // ---- block 1: self-attention ----
    ln_kernel<<<dim3(M), blk, 0, stream>>>(x, n1_g, n1_b, hb);
    gemm_rs_kernel<1><<<dim3(3 * D / 128, M / 128), blk, 0, stream>>>(
        hb, hb, wt_sqkv, sa_bq, sa_bk, sa_bv, qbuf, kbuf, vtbuf, M, 3 * D, D);
    attn4_kernel<true><<<dim3(S / 128, B * 16), blk, 0, stream>>>(qbuf, kbuf, vtbuf, abuf);
    gemm_db_kernel<<<dim3(D / 128, M / 128), blk, 0, stream>>>(
        abuf, wt_sao, sa_bo, x, x1, M, D, D, 8, 4);

    // ---- block 2: cross-attention (Q from hb, K/V from encoder) ----
    ln_kernel<<<dim3(M), blk, 0, stream>>>(x1, n2_g, n2_b, hb);
    gemm_rs_kernel<1><<<dim3(3 * D / 128, M / 128), blk, 0, stream>>>(
        hb, encb, wt_cqkv, ca_bq, ca_bk, ca_bv, qbuf, kbuf, vtbuf, M, 3 * D, D);
    attn4_kernel<false><<<dim3(S / 128, B * 16), blk, 0, stream>>>(qbuf, kbuf, vtbuf, abuf);
    gemm_db_kernel<<<dim3(D / 128, M / 128), blk, 0, stream>>>(
        abuf, wt_cao, ca_bo, x1, x2, M, D, D, 8, 4);

    // ---- block 3: feed-forward ----
    ln_kernel<<<dim3(M), blk, 0, stream>>>(x2, n3_g, n3_b, hb);
    gemm_rs_kernel<2><<<dim3(DFF / 128, M / 128), blk, 0, stream>>>(
        hb, hb, wt_ff1, ff_b1, nullptr, nullptr, ffh, nullptr, nullptr, M, DFF, D);
    gemm_db_kernel<<<dim3(D / 128, M / 128), blk, 0, stream>>>(
        ffh, wt_ff2, ff_b2, x2, out, M, D, DFF, 4, 8);
}

// Round 10
// 529.524 us; speedup vs baseline: 1.0225x; 1.0225x over previous
//
#include <hip/hip_runtime.h>
#include <hip/hip_bf16.h>

typedef short short8 __attribute__((ext_vector_type(8)));
typedef float f32x4 __attribute__((ext_vector_type(4)));

#define SEQ 2048
#define QSCALE 0.18033688011112042f   // 0.125 * log2(e): softmax done in base 2
#define PSHIFT 20.0f                  // fixed softmax shift (cancels in O = acc/l)
#define EXP2(x) __builtin_amdgcn_exp2f(x)

__device__ __forceinline__ unsigned short f2bf(float f) {
    unsigned int u = __builtin_bit_cast(unsigned int, f);
    unsigned int r = (u + 0x7fffu + ((u >> 16) & 1u)) >> 16;
    return (unsigned short)r;
}

// ---------------------------------------------------------------------------
// Batched weight transpose + fp32->bf16: 8 D x D weights in one launch.
// ---------------------------------------------------------------------------
__global__ __launch_bounds__(256)
void wtrans8_kernel(const float* w0, const float* w1, const float* w2, const float* w3,
                    const float* w4, const float* w5, const float* w6, const float* w7,
                    unsigned short* __restrict__ outbase)
{
    const float* Ws[8] = {w0, w1, w2, w3, w4, w5, w6, w7};
    const float* __restrict__ W = Ws[blockIdx.z];
    unsigned short* __restrict__ Wt = outbase + (size_t)blockIdx.z * 1024 * 1024;
    __shared__ float t[32][33];
    const int tx = threadIdx.x & 31;
    const int ty = threadIdx.x >> 5;
    const int nb = blockIdx.x * 32;
    const int kb = blockIdx.y * 32;
#pragma unroll
    for (int i = 0; i < 4; i++)
        t[ty + i * 8][tx] = W[(size_t)(kb + ty + i * 8) * 1024 + nb + tx];
    __syncthreads();
#pragma unroll
    for (int i = 0; i < 4; i++)
        Wt[(size_t)(nb + ty + i * 8) * 1024 + kb + tx] = f2bf(t[tx][ty + i * 8]);
}

// single weight transpose (for the two FFN shapes)
__global__ __launch_bounds__(256)
void wtrans_kernel(const float* __restrict__ W, unsigned short* __restrict__ Wt,
                   int Kd, int Nd)
{
    __shared__ float t[32][33];
    const int tx = threadIdx.x & 31;
    const int ty = threadIdx.x >> 5;
    const int nb = blockIdx.x * 32;
    const int kb = blockIdx.y * 32;
#pragma unroll
    for (int i = 0; i < 4; i++)
        t[ty + i * 8][tx] = W[(size_t)(kb + ty + i * 8) * Nd + nb + tx];
    __syncthreads();
#pragma unroll
    for (int i = 0; i < 4; i++)
        Wt[(size_t)(nb + ty + i * 8) * Kd + kb + tx] = f2bf(t[tx][ty + i * 8]);
}

// ---------------------------------------------------------------------------
// Elementwise fp32 -> bf16
// ---------------------------------------------------------------------------
__global__ __launch_bounds__(256)
void cvt_kernel(const float* __restrict__ in, unsigned short* __restrict__ out, int n)
{
    int i = (blockIdx.x * 256 + threadIdx.x) * 4;
    if (i < n) {
        float4 v = *(const float4*)(in + i);
        ushort4 o;
        o.x = f2bf(v.x); o.y = f2bf(v.y); o.z = f2bf(v.z); o.w = f2bf(v.w);
        *(ushort4*)(out + i) = o;
    }
}

// ---------------------------------------------------------------------------
// LayerNorm (torch-faithful: ddof=1, eps added to std). fp32 in -> bf16 out.
// ---------------------------------------------------------------------------
__global__ __launch_bounds__(256)
void ln_kernel(const float* __restrict__ x, const float* __restrict__ g,
               const float* __restrict__ bb, unsigned short* __restrict__ out)
{
    const int D = 1024;
    const int row = blockIdx.x;
    const float* xr = x + (size_t)row * D;
    float v[4];
    float s = 0.f, ss = 0.f;
#pragma unroll
    for (int i = 0; i < 4; i++) {
        v[i] = xr[threadIdx.x + i * 256];
        s += v[i];
        ss += v[i] * v[i];
    }
#pragma unroll
    for (int off = 1; off < 64; off <<= 1) {
        s  += __shfl_xor(s,  off, 64);
        ss += __shfl_xor(ss, off, 64);
    }
    __shared__ float red[8];
    const int wave = threadIdx.x >> 6;
    if ((threadIdx.x & 63) == 0) { red[wave] = s; red[4 + wave] = ss; }
    __syncthreads();
    s  = red[0] + red[1] + red[2] + red[3];
    ss = red[4] + red[5] + red[6] + red[7];
    float mean = s / D;
    float var  = fmaxf((ss - s * mean) / (D - 1), 0.f);
    float inv  = 1.f / (sqrtf(var) + 1e-6f);
#pragma unroll
    for (int i = 0; i < 4; i++) {
        int c = threadIdx.x + i * 256;
        out[(size_t)row * D + c] = f2bf(g[c] * (v[i] - mean) * inv + bb[c]);
    }
}

// ---------------------------------------------------------------------------
// Register-staged double-buffered GEMM (round-4-proven transport) for the
// QKV projection and FFN1 shapes. C[M,N] = A[M,K] @ Wt[N,K]^T + bias.
// 128x128 tile, BK=64, 4 waves, 2 LDS buffers. Per K-step: issue next
// tile's global_load_dwordx4 -> VGPR before compute (latency hides under
// 32 MFMA), vmcnt(0) + linear ds_write_b128 after, one barrier.
// MODE 1: projection GEMM. Section = n0>>10: 0 -> Q (from A, scaled QSCALE,
//         head layout [B,H,S,64]); 1 -> K (from A2); 2 -> V (from A2,
//         written TRANSPOSED [B,H,64,S]).
// MODE 2: relu -> bf16 row-major [M,N]    (FFN first GEMM, o0)
// ---------------------------------------------------------------------------
template <int MODE>
__global__ __launch_bounds__(256, 1)
void gemm_rs_kernel(const unsigned short* __restrict__ A,
                    const unsigned short* __restrict__ A2,
                    const unsigned short* __restrict__ Wt,
                    const float* __restrict__ b0,
                    const float* __restrict__ b1,
                    const float* __restrict__ b2,
                    unsigned short* __restrict__ o0,
                    unsigned short* __restrict__ o1,
                    unsigned short* __restrict__ o2,
                    int M, int N, int K)
{
    __shared__ unsigned short As[2][128 * 64];
    __shared__ unsigned short Bs[2][128 * 64];
    const int tid  = threadIdx.x;
    const int lane = tid & 63;
    const int wv   = tid >> 6;
    const int quad = lane >> 4;
    const int l16  = lane & 15;
    const int m0 = blockIdx.y * 128;
    const int n0 = blockIdx.x * 128;
    const int wm = (wv >> 1) << 6;
    const int wn = (wv & 1) << 6;
    const int sect = (MODE == 1) ? (n0 >> 10) : 0;
    const unsigned short* Asel = (MODE == 1 && sect != 0) ? A2 : A;

    const int rsub = lane >> 3;                    // 0..7 row within chunk
    const int cu8  = ((lane & 7) ^ rsub) * 8;      // swizzled source col (elems)
    const unsigned short* Ag = Asel + (size_t)(m0 + wv * 32 + rsub) * K + cu8;
    const unsigned short* Bg = Wt   + (size_t)(n0 + wv * 32 + rsub) * K + cu8;

    f32x4 acc[4][4];
#pragma unroll
    for (int i = 0; i < 4; i++)
#pragma unroll
        for (int j = 0; j < 4; j++) acc[i][j] = f32x4{0.f, 0.f, 0.f, 0.f};

    const int NT = K >> 6;

    short8 ar[4], br[4];   // in-flight staging registers (one tile)

    auto ldregs = [&](int t) {
        const int kb = t << 6;
#pragma unroll
        for (int r = 0; r < 4; r++) {
            ar[r] = *(const short8*)(Ag + (size_t)(r * 8) * K + kb);
            br[r] = *(const short8*)(Bg + (size_t)(r * 8) * K + kb);
        }
    };
    auto wrlds = [&](int b) {
#pragma unroll
        for (int r = 0; r < 4; r++) {
            *(short8*)&As[b][(wv * 4 + r) * 512 + lane * 8] = ar[r];
            *(short8*)&Bs[b][(wv * 4 + r) * 512 + lane * 8] = br[r];
        }
    };

    // prologue: tile 0 -> regs -> LDS[0]
    ldregs(0);
    asm volatile("s_waitcnt vmcnt(0)" ::: "memory");
    wrlds(0);
    asm volatile("s_waitcnt lgkmcnt(0)" ::: "memory");
    __builtin_amdgcn_s_barrier();

    for (int i = 0; i < NT; i++) {
        const int cur = i & 1;
        if (i + 1 < NT) ldregs(i + 1);   // issue early: latency under compute

#pragma unroll
        for (int ks = 0; ks < 2; ks++) {
            short8 af[4], bfr[4];
#pragma unroll
            for (int mi = 0; mi < 4; mi++)
                af[mi] = *(const short8*)(&As[cur][(wm + mi * 16 + l16) * 64 +
                             (((ks * 4 + quad) ^ (l16 & 7)) * 8)]);
#pragma unroll
            for (int ni = 0; ni < 4; ni++)
                bfr[ni] = *(const short8*)(&Bs[cur][(wn + ni * 16 + l16) * 64 +
                             (((ks * 4 + quad) ^ (l16 & 7)) * 8)]);
#pragma unroll
            for (int mi = 0; mi < 4; mi++)
#pragma unroll
                for (int ni = 0; ni < 4; ni++)
                    acc[mi][ni] = __builtin_amdgcn_mfma_f32_16x16x32_bf16(
                        af[mi], bfr[ni], acc[mi][ni], 0, 0, 0);
        }

        if (i + 1 < NT) {
            asm volatile("s_waitcnt vmcnt(0)" ::: "memory");
            wrlds(cur ^ 1);
            asm volatile("s_waitcnt lgkmcnt(0)" ::: "memory");
            __builtin_amdgcn_s_barrier();
        }
    }

    if (MODE == 1) {
        const float* bias = (sect == 0) ? b0 : ((sect == 1) ? b1 : b2);
        if (sect == 2) {
            // V: write transposed [B,H,64,S], 4 consecutive s packed per store
#pragma unroll
            for (int mi = 0; mi < 4; mi++)
#pragma unroll
                for (int ni = 0; ni < 4; ni++) {
                    const int cc = (n0 + wn + ni * 16 + l16) & 1023;
                    const int h = cc >> 6, d = cc & 63;
                    const float bv = bias[cc];
                    const int rowg = m0 + wm + mi * 16 + quad * 4;
                    const int b = rowg >> 11, s = rowg & 2047;
                    ushort4 o4;
                    o4.x = f2bf(acc[mi][ni][0] + bv);
                    o4.y = f2bf(acc[mi][ni][1] + bv);
                    o4.z = f2bf(acc[mi][ni][2] + bv);
                    o4.w = f2bf(acc[mi][ni][3] + bv);
                    *(ushort4*)&o2[((size_t)(b * 16 + h) * 64 + d) * SEQ + s] = o4;
                }
        } else {
            unsigned short* dst = (sect == 0) ? o0 : o1;
            const float scl = (sect == 0) ? QSCALE : 1.0f;
#pragma unroll
            for (int mi = 0; mi < 4; mi++)
#pragma unroll
                for (int ni = 0; ni < 4; ni++) {
                    const int cc = (n0 + wn + ni * 16 + l16) & 1023;
                    const int h = cc >> 6, d = cc & 63;
                    const float bv = bias[cc];
#pragma unroll
                    for (int r = 0; r < 4; r++) {
                        const int rowg = m0 + wm + mi * 16 + quad * 4 + r;
                        const int b = rowg >> 11, s = rowg & 2047;
                        float v = (acc[mi][ni][r] + bv) * scl;
                        dst[((size_t)(b * 16 + h) * SEQ + s) * 64 + d] = f2bf(v);
                    }
                }
        }
    } else {
#pragma unroll
        for (int mi = 0; mi < 4; mi++)
#pragma unroll
            for (int ni = 0; ni < 4; ni++) {
                const int colg = n0 + wn + ni * 16 + l16;
                const float bv = b0[colg];
#pragma unroll
                for (int r = 0; r < 4; r++) {
                    const int rowg = m0 + wm + mi * 16 + quad * 4 + r;
                    float v = acc[mi][ni][r] + bv;
                    o0[(size_t)rowg * N + colg] = f2bf(fmaxf(v, 0.f));
                }
            }
    }
}

// ---------------------------------------------------------------------------
// Register-staged double-buffered GEMM for the N=1024 shapes (round-4 WIN:
// reg-staging >> global_load_lds at 1-2 blocks/CU).
// C[M,N] = A[M,K] @ Wt[N,K]^T + bias + res   (fp32 out, fused residual)
// 128x128 tile, BK=64, 4 waves, 2 LDS buffers.
// XCD rectangle partition (cm x cn tiles per XCD): FETCH 143 -> 57 MB.
// LDS reads XOR-swizzled; swizzle pre-applied to global source addr.
// ---------------------------------------------------------------------------
__global__ __launch_bounds__(256, 1)
void gemm_db_kernel(const unsigned short* __restrict__ A,
                    const unsigned short* __restrict__ Wt,
                    const float* __restrict__ b0,
                    const float* __restrict__ res,
                    float* __restrict__ outf,
                    int M, int N, int K, int cm, int cn)
{
    __shared__ unsigned short As[2][128 * 64];
    __shared__ unsigned short Bs[2][128 * 64];
    const int tid  = threadIdx.x;
    const int lane = tid & 63;
    const int wv   = tid >> 6;
    const int quad = lane >> 4;
    const int l16  = lane & 15;
    // XCD partition: id%8 == XCD (round-robin dispatch heuristic)
    const int NX  = gridDim.x;
    const int id  = blockIdx.y * NX + blockIdx.x;
    const int xcd = id & 7, slot = id >> 3;
    const int ngx = NX / cn;                 // #col-groups of XCD rectangles
    const int rg = xcd / ngx, cg = xcd - rg * ngx;
    const int m0 = (rg * cm + (slot % cm)) * 128;
    const int n0 = (cg * cn + (slot / cm)) * 128;
    const int wm = (wv >> 1) << 6;
    const int wn = (wv & 1) << 6;

    const int rsub = lane >> 3;                    // 0..7 row within chunk
    const int cu8  = ((lane & 7) ^ rsub) * 8;      // swizzled source col (elems)
    const unsigned short* Ag = A  + (size_t)(m0 + wv * 32 + rsub) * K + cu8;
    const unsigned short* Bg = Wt + (size_t)(n0 + wv * 32 + rsub) * K + cu8;

    f32x4 acc[4][4];
#pragma unroll
    for (int i = 0; i < 4; i++)
#pragma unroll
        for (int j = 0; j < 4; j++) acc[i][j] = f32x4{0.f, 0.f, 0.f, 0.f};

    const int NT = K >> 6;

    short8 ar[4], br[4];   // in-flight staging registers (one tile)

    auto ldregs = [&](int t) {
        const int kb = t << 6;
#pragma unroll
        for (int r = 0; r < 4; r++) {
            ar[r] = *(const short8*)(Ag + (size_t)(r * 8) * K + kb);
            br[r] = *(const short8*)(Bg + (size_t)(r * 8) * K + kb);
        }
    };
    auto wrlds = [&](int b) {
#pragma unroll
        for (int r = 0; r < 4; r++) {
            *(short8*)&As[b][(wv * 4 + r) * 512 + lane * 8] = ar[r];
            *(short8*)&Bs[b][(wv * 4 + r) * 512 + lane * 8] = br[r];
        }
    };

    // prologue: tile 0 -> regs -> LDS[0]
    ldregs(0);
    asm volatile("s_waitcnt vmcnt(0)" ::: "memory");
    wrlds(0);
    asm volatile("s_waitcnt lgkmcnt(0)" ::: "memory");
    __builtin_amdgcn_s_barrier();

    for (int i = 0; i < NT; i++) {
        const int cur = i & 1;
        if (i + 1 < NT) ldregs(i + 1);   // issue early: latency under compute

        // compute buffer cur: 2 K-slices x 16 MFMA
#pragma unroll
        for (int ks = 0; ks < 2; ks++) {
            short8 af[4], bfr[4];
#pragma unroll
            for (int mi = 0; mi < 4; mi++)
                af[mi] = *(const short8*)(&As[cur][(wm + mi * 16 + l16) * 64 +
                             (((ks * 4 + quad) ^ (l16 & 7)) * 8)]);
#pragma unroll
            for (int ni = 0; ni < 4; ni++)
                bfr[ni] = *(const short8*)(&Bs[cur][(wn + ni * 16 + l16) * 64 +
                             (((ks * 4 + quad) ^ (l16 & 7)) * 8)]);
#pragma unroll
            for (int mi = 0; mi < 4; mi++)
#pragma unroll
                for (int ni = 0; ni < 4; ni++)
                    acc[mi][ni] = __builtin_amdgcn_mfma_f32_16x16x32_bf16(
                        af[mi], bfr[ni], acc[mi][ni], 0, 0, 0);
        }

        if (i + 1 < NT) {
            // regs arrived during compute; publish to the other buffer
            asm volatile("s_waitcnt vmcnt(0)" ::: "memory");
            wrlds(cur ^ 1);
            asm volatile("s_waitcnt lgkmcnt(0)" ::: "memory");
            __builtin_amdgcn_s_barrier();   // buffer cur^1 ready for all
        }
    }

    // epilogue: bias + fused residual, fp32 out
#pragma unroll
    for (int mi = 0; mi < 4; mi++)
#pragma unroll
        for (int ni = 0; ni < 4; ni++) {
            const int colg = n0 + wn + ni * 16 + l16;
            const float bv = b0[colg];
#pragma unroll
            for (int r = 0; r < 4; r++) {
                const int rowg = m0 + wm + mi * 16 + quad * 4 + r;
                outf[(size_t)rowg * N + colg] =
                    acc[mi][ni][r] + bv + res[(size_t)rowg * N + colg];
            }
        }
}

// ---------------------------------------------------------------------------
// Flash attention v4e: round-9 structure (known-good) with two VALU cuts in
// the softmax phase, layout/addresses untouched:
//  (1) PSHIFT folded into the QK MFMA accumulator init (C = -PSHIFT) --
//      deletes 64 v_sub per tile; identical values.
//  (2) P->bf16 via __float2bfloat16 (COMPILER-lowered HW cvt; m240: the
//      compiler path is safe -- rounds 5/6/8 proved hand-asm cvt_pk is not)
//      -- replaces the 4-int-op manual f2bf (saves ~192 VALU ops/tile).
// ---------------------------------------------------------------------------
template <bool CAUSAL>
__global__ __launch_bounds__(256, 2)
void attn4_kernel(const unsigned short* __restrict__ Q,
                  const unsigned short* __restrict__ K,
                  const unsigned short* __restrict__ VT,
                  unsigned short* __restrict__ O)
{
    __shared__ unsigned short Ks[128 * 72];
    __shared__ unsigned short Vt[64 * 136];
    __shared__ unsigned short Ps[4][32 * 136];
    __shared__ float sumS[4][32];
    const int tid  = threadIdx.x;
    const int lane = tid & 63;
    const int wave = tid >> 6;
    const int quad = lane >> 4;
    const int l16  = lane & 15;
    const int bh = blockIdx.y;
    // causal: pair heavy with light so each CU's two blocks sum to 17 tiles
    const int qb = (CAUSAL && (bh & 16)) ? (15 - (int)blockIdx.x) : (int)blockIdx.x;
    const int q0 = qb * 128;
    const size_t baseK = (size_t)bh * SEQ * 64;
    const size_t baseV = (size_t)bh * 64 * SEQ;

    short8 aq[2][2];
#pragma unroll
    for (int qs = 0; qs < 2; qs++) {
        const unsigned short* qp =
            Q + baseK + (size_t)(q0 + wave * 32 + qs * 16 + l16) * 64 + quad * 8;
        aq[qs][0] = *(const short8*)(qp);
        aq[qs][1] = *(const short8*)(qp + 32);
    }
    f32x4 acc[4][2];   // [mi(d)][qs]: O^T row d=mi*16+quad*4+r, col q=l16
#pragma unroll
    for (int i = 0; i < 4; i++)
#pragma unroll
        for (int j = 0; j < 2; j++) acc[i][j] = f32x4{0.f, 0.f, 0.f, 0.f};
    float lsum[2][4] = {{0.f, 0.f, 0.f, 0.f}, {0.f, 0.f, 0.f, 0.f}};

    const int nkb = CAUSAL ? (qb + 1) : (SEQ / 128);
    const int krow = tid >> 1;
    const int kc   = (tid & 1) * 32;
    const int vrow = tid >> 2;
    const int vc   = (tid & 3) * 32;
    const unsigned short* kg = K  + baseK + (size_t)krow * 64 + kc;
    const unsigned short* vg = VT + baseV + (size_t)vrow * SEQ + vc;

    short8 kr0 = *(const short8*)(kg),      kr1 = *(const short8*)(kg + 8);
    short8 kr2 = *(const short8*)(kg + 16), kr3 = *(const short8*)(kg + 24);
    short8 vr0 = *(const short8*)(vg),      vr1 = *(const short8*)(vg + 8);
    short8 vr2 = *(const short8*)(vg + 16), vr3 = *(const short8*)(vg + 24);

    for (int kb = 0; kb < nkb; kb++) {
        __syncthreads();
        *(short8*)&Ks[krow * 72 + kc]      = kr0;
        *(short8*)&Ks[krow * 72 + kc + 8]  = kr1;
        *(short8*)&Ks[krow * 72 + kc + 16] = kr2;
        *(short8*)&Ks[krow * 72 + kc + 24] = kr3;
        *(short8*)&Vt[vrow * 136 + vc]      = vr0;
        *(short8*)&Vt[vrow * 136 + vc + 8]  = vr1;
        *(short8*)&Vt[vrow * 136 + vc + 16] = vr2;
        *(short8*)&Vt[vrow * 136 + vc + 24] = vr3;
        if (kb + 1 < nkb) {
            const unsigned short* kg2 = kg + (size_t)(kb + 1) * 128 * 64;
            const unsigned short* vg2 = vg + (size_t)(kb + 1) * 128;
            kr0 = *(const short8*)(kg2);      kr1 = *(const short8*)(kg2 + 8);
            kr2 = *(const short8*)(kg2 + 16); kr3 = *(const short8*)(kg2 + 24);
            vr0 = *(const short8*)(vg2);      vr1 = *(const short8*)(vg2 + 8);
            vr2 = *(const short8*)(vg2 + 16); vr3 = *(const short8*)(vg2 + 24);
        }
        __syncthreads();

        const bool maskTile = CAUSAL && (kb == nkb - 1);
        // QK^T: Ks fragments are qs-invariant -> load once, use for both qs.
        // Accumulator starts at -PSHIFT: MFMA's C-add does the softmax shift.
        f32x4 scf[2][8];
#pragma unroll
        for (int nt = 0; nt < 8; nt++) {
            short8 bk0 = *(const short8*)(&Ks[(nt * 16 + l16) * 72 + quad * 8]);
            short8 bk1 = *(const short8*)(&Ks[(nt * 16 + l16) * 72 + 32 + quad * 8]);
#pragma unroll
            for (int qs = 0; qs < 2; qs++) {
                f32x4 z = f32x4{-PSHIFT, -PSHIFT, -PSHIFT, -PSHIFT};
                z = __builtin_amdgcn_mfma_f32_16x16x32_bf16(aq[qs][0], bk0, z, 0, 0, 0);
                z = __builtin_amdgcn_mfma_f32_16x16x32_bf16(aq[qs][1], bk1, z, 0, 0, 0);
                scf[qs][nt] = z;
            }
        }
#pragma unroll
        for (int qs = 0; qs < 2; qs++) {
            if (maskTile) {
                const int qg = q0 + wave * 32 + qs * 16 + quad * 4;
                const int k0 = kb * 128;
#pragma unroll
                for (int nt = 0; nt < 8; nt++) {
                    const int kg_ = k0 + nt * 16 + l16;
#pragma unroll
                    for (int r = 0; r < 4; r++)
                        if (kg_ > qg + r) scf[qs][nt][r] = -1e9f;
                }
            }
#pragma unroll
            for (int nt = 0; nt < 8; nt++)
#pragma unroll
                for (int r = 0; r < 4; r++) {
                    float pv = EXP2(scf[qs][nt][r]);   // shift already folded in
                    lsum[qs][r] += pv;
                    Ps[wave][(qs * 16 + quad * 4 + r) * 136 +
                             ((nt * 16 + l16) ^ (quad * 8))] =
                        __builtin_bit_cast(unsigned short, __float2bfloat16(pv));
                }
        }
        // O^T += V^T @ P^T, both operands contiguous b128; Vt reads shared
        const int pswz = 8 * (quad ^ ((l16 >> 2) & 3));
#pragma unroll
        for (int c = 0; c < 4; c++) {
            short8 av[4];
#pragma unroll
            for (int mi = 0; mi < 4; mi++)
                av[mi] = *(const short8*)(&Vt[(mi * 16 + l16) * 136 + c * 32 + quad * 8]);
#pragma unroll
            for (int qs = 0; qs < 2; qs++) {
                short8 bp = *(const short8*)(&Ps[wave][(qs * 16 + l16) * 136 + c * 32 + pswz]);
#pragma unroll
                for (int mi = 0; mi < 4; mi++)
                    acc[mi][qs] = __builtin_amdgcn_mfma_f32_16x16x32_bf16(av[mi], bp, acc[mi][qs], 0, 0, 0);
            }
        }
    }
#pragma unroll
    for (int qs = 0; qs < 2; qs++)
#pragma unroll
        for (int r = 0; r < 4; r++) {
#pragma unroll
            for (int off = 1; off < 16; off <<= 1)
                lsum[qs][r] += __shfl_xor(lsum[qs][r], off, 64);
        }
    if (l16 == 0) {
#pragma unroll
        for (int qs = 0; qs < 2; qs++)
#pragma unroll
            for (int r = 0; r < 4; r++)
                sumS[wave][qs * 16 + quad * 4 + r] = lsum[qs][r];
    }
    __syncthreads();
    const int b = bh >> 4, h = bh & 15;
#pragma unroll
    for (int qs = 0; qs < 2; qs++) {
        const float rcpL = 1.f / sumS[wave][qs * 16 + l16];
        const int qg = q0 + wave * 32 + qs * 16 + l16;
#pragma unroll
        for (int mi = 0; mi < 4; mi++) {
            ushort4 o4;
            o4.x = f2bf(acc[mi][qs][0] * rcpL);
            o4.y = f2bf(acc[mi][qs][1] * rcpL);
            o4.z = f2bf(acc[mi][qs][2] * rcpL);
            o4.w = f2bf(acc[mi][qs][3] * rcpL);
            *(ushort4*)&O[(size_t)(b * SEQ + qg) * 1024 + h * 64 + mi * 16 + quad * 4] = o4;
        }
    }
}

// ---------------------------------------------------------------------------
extern "C" void kernel_launch(void* const* d_in, const int* in_sizes, int n_in,
                              void* d_out, int out_size, void* d_ws, size_t ws_size,
                              hipStream_t stream)
{
    (void)in_sizes; (void)n_in; (void)out_size; (void)ws_size;
    const int B = 2, S = SEQ, D = 1024, DFF = 4096;
    const int M = B * S;  // 4096

    const float* x     = (const float*)d_in[0];
    const float* enc   = (const float*)d_in[1];
    const float* sa_wq = (const float*)d_in[4],  *sa_bq = (const float*)d_in[5];
    const float* sa_wk = (const float*)d_in[6],  *sa_bk = (const float*)d_in[7];
    const float* sa_wv = (const float*)d_in[8],  *sa_bv = (const float*)d_in[9];
    const float* sa_wo = (const float*)d_in[10], *sa_bo = (const float*)d_in[11];
    const float* ca_wq = (const float*)d_in[12], *ca_bq = (const float*)d_in[13];
    const float* ca_wk = (const float*)d_in[14], *ca_bk = (const float*)d_in[15];
    const float* ca_wv = (const float*)d_in[16], *ca_bv = (const float*)d_in[17];
    const float* ca_wo = (const float*)d_in[18], *ca_bo = (const float*)d_in[19];
    const float* ff_w1 = (const float*)d_in[20], *ff_b1 = (const float*)d_in[21];
    const float* ff_w2 = (const float*)d_in[22], *ff_b2 = (const float*)d_in[23];
    const float* n1_g  = (const float*)d_in[24], *n1_b = (const float*)d_in[25];
    const float* n2_g  = (const float*)d_in[26], *n2_b = (const float*)d_in[27];
    const float* n3_g  = (const float*)d_in[28], *n3_b = (const float*)d_in[29];
    float* out = (float*)d_out;

    char* p = (char*)d_ws;
    auto carve = [&](size_t bytes) -> char* {
        char* r = p;
        p += (bytes + 255) & ~(size_t)255;
        return r;
    };
    unsigned short* wt8     = (unsigned short*)carve((size_t)8 * D * D * 2);
    unsigned short* wt_sqkv = wt8;                       // saq, sak, sav contiguous
    unsigned short* wt_sao  = wt8 + (size_t)3 * D * D;
    unsigned short* wt_cqkv = wt8 + (size_t)4 * D * D;   // caq, cak, cav contiguous
    unsigned short* wt_cao  = wt8 + (size_t)7 * D * D;
    unsigned short* wt_ff1  = (unsigned short*)carve((size_t)D * DFF * 2);
    unsigned short* wt_ff2  = (unsigned short*)carve((size_t)DFF * D * 2);
    unsigned short* encb    = (unsigned short*)carve((size_t)M * D * 2);
    unsigned short* hb      = (unsigned short*)carve((size_t)M * D * 2);
    unsigned short* qbuf    = (unsigned short*)carve((size_t)M * D * 2);
    unsigned short* kbuf    = (unsigned short*)carve((size_t)M * D * 2);
    unsigned short* vtbuf   = (unsigned short*)carve((size_t)M * D * 2);
    unsigned short* ffh     = (unsigned short*)carve((size_t)M * DFF * 2);
    float* x1 = (float*)carve((size_t)M * D * 4);
    unsigned short* abuf = hb;   // lifetimes disjoint
    float* x2 = out;             // block-2 residual in d_out; block-3 in-place

    dim3 blk(256);
    wtrans8_kernel<<<dim3(32, 32, 8), blk, 0, stream>>>(
        sa_wq, sa_wk, sa_wv, sa_wo, ca_wq, ca_wk, ca_wv, ca_wo, wt8);
    wtrans_kernel<<<dim3(DFF / 32, D / 32), blk, 0, stream>>>(ff_w1, wt_ff1, D, DFF);
    wtrans_kernel<<<dim3(D / 32, DFF / 32), blk, 0, stream>>>(ff_w2, wt_ff2, DFF, D);
    cvt_kernel<<<dim3(M * D / 1024), blk, 0, stream>>>(enc, encb, M * D);

    // ---- block 1: self-attention ----
    ln_kernel<<<dim3(M), blk, 0, stream>>>(x, n1_g, n1_b, hb);
    gemm_rs_kernel<1><<<dim3(3 * D / 128, M / 128), blk, 0, stream>>>(
        hb, hb, wt_sqkv, sa_bq, sa_bk, sa_bv, qbuf, kbuf, vtbuf, M, 3 * D, D);
    attn4_kernel<true><<<dim3(S / 128, B * 16), blk, 0, stream>>>(qbuf, kbuf, vtbuf, abuf);
    gemm_db_kernel<<<dim3(D / 128, M / 128), blk, 0, stream>>>(
        abuf, wt_sao, sa_bo, x, x1, M, D, D, 8, 4);

    // ---- block 2: cross-attention (Q from hb, K/V from encoder) ----
    ln_kernel<<<dim3(M), blk, 0, stream>>>(x1, n2_g, n2_b, hb);
    gemm_rs_kernel<1><<<dim3(3 * D / 128, M / 128), blk, 0, stream>>>(
        hb, encb, wt_cqkv, ca_bq, ca_bk, ca_bv, qbuf, kbuf, vtbuf, M, 3 * D, D);
    attn4_kernel<false><<<dim3(S / 128, B * 16), blk, 0, stream>>>(qbuf, kbuf, vtbuf, abuf);
    gemm_db_kernel<<<dim3(D / 128, M / 128), blk, 0, stream>>>(
        abuf, wt_cao, ca_bo, x1, x2, M, D, D, 8, 4);

    // ---- block 3: feed-forward ----
    ln_kernel<<<dim3(M), blk, 0, stream>>>(x2, n3_g, n3_b, hb);
    gemm_rs_kernel<2><<<dim3(DFF / 128, M / 128), blk, 0, stream>>>(
        hb, hb, wt_ff1, ff_b1, nullptr, nullptr, ffh, nullptr, nullptr, M, DFF, D);
    gemm_db_kernel<<<dim3(D / 128, M / 128), blk, 0, stream>>>(
        ffh, wt_ff2, ff_b2, x2, out, M, D, DFF, 4, 8);
}